// Round 19
// baseline (91.908 us; speedup 1.0000x reference)
//
#include <hip/hip_runtime.h>

typedef __attribute__((ext_vector_type(8))) short bf16x8;
typedef __attribute__((ext_vector_type(4))) float f32x4;
typedef __attribute__((ext_vector_type(16))) float f32x16;

#define T_SEQ 1024
#define NH 16
#define CEMB 1024

__device__ __forceinline__ float asf(unsigned int u){ union{unsigned int i;float f;}x; x.i=u; return x.f; }
__device__ __forceinline__ float bf2f(unsigned short u){ return asf(((unsigned int)u)<<16); }
__device__ __forceinline__ unsigned short f2bf(float f){
  union{float f;unsigned int i;}x; x.f=f;
  unsigned int r = x.i + 0x7FFFu + ((x.i>>16)&1u);
  return (unsigned short)(r>>16);
}
__device__ __forceinline__ f32x4 MFMA16(bf16x8 a, bf16x8 b, f32x4 c){
  return __builtin_amdgcn_mfma_f32_16x16x32_bf16(a, b, c, 0,0,0);
}

// ---------------- fused prep, heavy-first: gates (0-1023) | wtrans (1024-4095) | cvt (4096-8191) ----------------
__global__ __launch_bounds__(256)
void prep_all_kernel(const float* __restrict__ x, unsigned short* __restrict__ x_bf,
                     const float* __restrict__ Wqk, unsigned short* __restrict__ WqkT,
                     const float* __restrict__ Wproj, unsigned short* __restrict__ WprojT,
                     const float* __restrict__ Wg, const float* __restrict__ bg,
                     float* __restrict__ gates){
  __shared__ float tile[32][33];
  const int tid = threadIdx.x;
  int blk = blockIdx.x;
  if (blk < 1024){
    // ---- gates (heaviest blocks first) ----
    const int lane = tid & 63;
    const int row  = blk*4 + (tid>>6);
    const float* xr = x + (size_t)row*CEMB;
    float acc[NH];
    #pragma unroll
    for (int h=0;h<NH;h++) acc[h]=0.f;
    for (int i=0;i<CEMB/64;i++){
      float xv = xr[i*64 + lane];
      const float4* wg = reinterpret_cast<const float4*>(Wg + (size_t)(i*64+lane)*NH);
      float4 a=wg[0], b=wg[1], c=wg[2], d=wg[3];
      acc[0]+=xv*a.x; acc[1]+=xv*a.y; acc[2]+=xv*a.z; acc[3]+=xv*a.w;
      acc[4]+=xv*b.x; acc[5]+=xv*b.y; acc[6]+=xv*b.z; acc[7]+=xv*b.w;
      acc[8]+=xv*c.x; acc[9]+=xv*c.y; acc[10]+=xv*c.z; acc[11]+=xv*c.w;
      acc[12]+=xv*d.x; acc[13]+=xv*d.y; acc[14]+=xv*d.z; acc[15]+=xv*d.w;
    }
    #pragma unroll
    for (int h=0;h<NH;h++){
      #pragma unroll
      for (int m=32;m;m>>=1) acc[h] += __shfl_xor(acc[h], m, 64);
    }
    float mx = -1e30f;
    #pragma unroll
    for (int h=0;h<NH;h++){ acc[h] += bg[h]; mx = fmaxf(mx, acc[h]); }
    float s = 0.f;
    #pragma unroll
    for (int h=0;h<NH;h++){ acc[h] = __expf(acc[h]-mx); s += acc[h]; }
    float g = 0.f;
    #pragma unroll
    for (int h=0;h<NH;h++) g = (lane==h) ? acc[h]/s : g;
    if (lane < NH) gates[(size_t)row*NH + lane] = g;
  } else if (blk < 4096){
    // ---- weight transposes ----
    blk -= 1024;
    const float* W; unsigned short* Wt; int R, C, bx, by;
    if (blk < 2048){ W = Wqk;   Wt = WqkT;   R = 1024; C = 2048; bx = blk & 63; by = blk >> 6; }
    else { blk -= 2048; W = Wproj; Wt = WprojT; R = 1024; C = 1024; bx = blk & 31; by = blk >> 5; }
    const int c0 = bx*32, r0 = by*32;
    const int tx = tid & 31, ty = tid >> 5;   // (32,8)
    #pragma unroll
    for (int i=0;i<32;i+=8) tile[ty+i][tx] = W[(size_t)(r0+ty+i)*C + c0 + tx];
    __syncthreads();
    #pragma unroll
    for (int i=0;i<32;i+=8) Wt[(size_t)(c0+ty+i)*R + r0 + tx] = f2bf(tile[tx][ty+i]);
  } else {
    // ---- cvt x -> bf16 ----
    int i = ((blk-4096)*256 + tid)*4;
    float4 v = *reinterpret_cast<const float4*>(x + i);
    ushort4 o; o.x=f2bf(v.x); o.y=f2bf(v.y); o.z=f2bf(v.z); o.w=f2bf(v.w);
    *reinterpret_cast<ushort4*>(x_bf + i) = o;
  }
}

// ---------------- bf16 MFMA GEMM, depth-2 counted-vmcnt pipeline, 32x32x16 MFMA ----------------
// Wave owns one 32-row strip of NT 32x32 tiles: gemm1 (BM=128) 32x64 (NT=2),
// gemm2 (BM=64) 32x32 (NT=1). 32x32x16 = 17% less MFMA pipe time than 16x16x32
// (m119: 8.07cy/32KFLOP vs 9.7) and 12 vs 16 ds_read_b128 per K-64.
// C/D mapping (HW-verified): col=lane&31, row=(reg&3)+8*(reg>>2)+4*(lane>>5).
template<bool OUT_BF16, int BM, bool PACK, int NW>
__global__ __launch_bounds__(NW*64)
void gemm_bt_kernel(const unsigned short* __restrict__ A, const unsigned short* __restrict__ Bt,
                    const float* __restrict__ bias, void* __restrict__ Cptr,
                    int M, int N, int K,
                    unsigned short* __restrict__ Kpack, unsigned short* __restrict__ Vpack){
  constexpr int WRN   = BM/32;                   // 4 (BM=128) / 2 (BM=64)
  constexpr int WCN   = NW/WRN;                  // 2 / 4
  constexpr int WCW   = 128/WCN;                 // 64 / 32
  constexpr int NT    = WCW/32;                  // 2 / 1
  constexpr int AISS  = BM/(NW*8);               // A stage issues per thread
  constexpr int BISS  = 128/(NW*8);              // B stage issues per thread
  constexpr int LDSN  = BM*64*2 + 128*64*2;
  __shared__ __align__(16) unsigned short smem[LDSN];
  unsigned short* lA0 = smem;
  unsigned short* lA1 = smem + BM*64;
  unsigned short* lB0 = smem + BM*64*2;
  unsigned short* lB1 = smem + BM*64*2 + 128*64;
  const int tid = threadIdx.x;
  const int wid = tid>>6, lane = tid&63;
  const int nbm = M/BM;
  const int bid = blockIdx.x;
  const int bm = bid % nbm, bn = bid / nbm;
  const int wr = wid/WCN;
  const int wc = wid%WCN;
  f32x16 acc[NT] = {};

  const unsigned short* gA = A + (size_t)bm*BM*K;
  const unsigned short* gB = Bt + (size_t)bn*128*K;
  const int srow = lane>>3;
  const int schunk = lane&7;

#define GSTAGE(LA, LB, KK) do { \
  _Pragma("unroll") \
  for (int i_=0;i_<AISS;i_++){ \
    int rowi_ = (wid*AISS+i_)*8 + srow; \
    int cc_ = schunk ^ (rowi_ & 7); \
    __builtin_amdgcn_global_load_lds((const __attribute__((address_space(1))) void*)(gA + (size_t)rowi_*K + (KK) + cc_*8), \
        (__attribute__((address_space(3))) void*)&LA[(wid*AISS+i_)*512], 16, 0, 0); \
  } \
  _Pragma("unroll") \
  for (int i_=0;i_<BISS;i_++){ \
    int rowi_ = (wid*BISS+i_)*8 + srow; \
    int cc_ = schunk ^ (rowi_ & 7); \
    __builtin_amdgcn_global_load_lds((const __attribute__((address_space(1))) void*)(gB + (size_t)rowi_*K + (KK) + cc_*8), \
        (__attribute__((address_space(3))) void*)&LB[(wid*BISS+i_)*512], 16, 0, 0); \
  } \
} while(0)

// 32x32x16: K=64 tile = 4 ks steps of K=16 (2 chunks each, group = lane>>5).
#define GCOMPUTE(LA, LB) do { \
  _Pragma("unroll") \
  for (int ks_=0; ks_<4; ks_++){ \
    bf16x8 af_, bf_[NT]; \
    { int r_ = wr*32 + (lane&31); \
      int p_ = (ks_*2 + (lane>>5)) ^ (r_&7); \
      af_ = *reinterpret_cast<const bf16x8*>(&LA[r_*64 + p_*8]); } \
    _Pragma("unroll") \
    for (int n_=0;n_<NT;n_++){ \
      int r_ = wc*WCW + n_*32 + (lane&31); \
      int p_ = (ks_*2 + (lane>>5)) ^ (r_&7); \
      bf_[n_] = *reinterpret_cast<const bf16x8*>(&LB[r_*64 + p_*8]); \
    } \
    _Pragma("unroll") \
    for (int n_=0;n_<NT;n_++) \
      acc[n_] = __builtin_amdgcn_mfma_f32_32x32x16_bf16(af_, bf_[n_], acc[n_], 0,0,0); \
  } \
} while(0)

#define WAITL do { \
  if      constexpr (AISS+BISS==3) asm volatile("s_waitcnt vmcnt(3)" ::: "memory"); \
  else if constexpr (AISS+BISS==4) asm volatile("s_waitcnt vmcnt(4)" ::: "memory"); \
  else if constexpr (AISS+BISS==6) asm volatile("s_waitcnt vmcnt(6)" ::: "memory"); \
  else                             asm volatile("s_waitcnt vmcnt(8)" ::: "memory"); \
  __builtin_amdgcn_s_barrier(); \
  __builtin_amdgcn_sched_barrier(0); \
} while(0)

  GSTAGE(lA0, lB0, 0);
  GSTAGE(lA1, lB1, 64);
  for (int k0=0; k0<K-128; k0+=128){
    WAITL;
    GCOMPUTE(lA0, lB0);
    __builtin_amdgcn_s_barrier();
    __builtin_amdgcn_sched_barrier(0);
    GSTAGE(lA0, lB0, k0+128);
    WAITL;
    GCOMPUTE(lA1, lB1);
    __builtin_amdgcn_s_barrier();
    __builtin_amdgcn_sched_barrier(0);
    GSTAGE(lA1, lB1, k0+192);
  }
  WAITL;
  GCOMPUTE(lA0, lB0);
  asm volatile("s_waitcnt vmcnt(0)" ::: "memory");
  __builtin_amdgcn_s_barrier();
  __builtin_amdgcn_sched_barrier(0);
  GCOMPUTE(lA1, lB1);
#undef GSTAGE
#undef GCOMPUTE
#undef WAITL

  const int c32 = lane&31;
  const int hi  = lane>>5;

  if constexpr (PACK){
    if (bn >= 8){
      // ---- pack epilogue: stage tile (stride 136), emit Kpack/Vpack frags ----
      __syncthreads();
      #pragma unroll
      for (int n=0;n<NT;n++){
        const int c_l = wc*WCW + n*32 + c32;
        const float bv = bias[bn*128 + c_l];
        #pragma unroll
        for (int rg=0;rg<16;rg++){
          const int r_l = wr*32 + (rg&3) + 8*(rg>>2) + 4*hi;
          smem[r_l*136 + c_l] = f2bf(acc[n][rg] + bv);
        }
      }
      __syncthreads();
      const int b = bm>>3;
      const int ktg0 = (bm&7)*4;
      const int g = lane>>4, li = lane&15;
      const int kt_l = wid>>1;          // 0..3: 32-row kt tile
      const int hh   = wid&1;           // head half
      const int bh = b*NH + (bn-8)*2 + hh;
      const size_t fb = ((size_t)bh*32 + ktg0 + kt_l)*4;
      #pragma unroll
      for (int f=0; f<4; f++){
        // Kpack[bh][kt][f][lane][j] = K[kt*32+(f>>1)*16+li][(f&1)*32+g*8+j]
        uint4 kv = *reinterpret_cast<const uint4*>(
            &smem[(kt_l*32 + ((f>>1)<<4) + li)*136 + hh*64 + (f&1)*32 + g*8]);
        *reinterpret_cast<uint4*>(Kpack + ((fb + f)*64 + lane)*8) = kv;
        // Vpack[bh][kt][d4][lane][j] = K[kt*32+g*8+j][d4*16+li]   (d4 = f)
        unsigned short vv[8];
        #pragma unroll
        for (int j=0;j<8;j++) vv[j] = smem[(kt_l*32 + g*8 + j)*136 + hh*64 + f*16 + li];
        *reinterpret_cast<uint4*>(Vpack + ((fb + f)*64 + lane)*8) = *reinterpret_cast<const uint4*>(vv);
      }
      return;
    }
  }

  #pragma unroll
  for (int n=0;n<NT;n++){
    const int col = bn*128 + wc*WCW + n*32 + c32;
    const float bv = bias[col];
    #pragma unroll
    for (int rg=0;rg<16;rg++){
      const int row = bm*BM + wr*32 + (rg&3) + 8*(rg>>2) + 4*hi;
      const float v = acc[n][rg] + bv;
      if (OUT_BF16) ((unsigned short*)Cptr)[(size_t)row*N + col] = f2bf(v);
      else          ((float*)Cptr)[(size_t)row*N + col] = v;
    }
  }
}

// ---------------- MFMA attention, no-max softmax, packed frags, NO split-K ----------------
__global__ __launch_bounds__(256)
void attn_mfma_kernel(const unsigned short* __restrict__ qk,
                      const unsigned short* __restrict__ Kpack,
                      const unsigned short* __restrict__ Vpack,
                      const float* __restrict__ gates, unsigned short* __restrict__ gated){
  __shared__ unsigned short lP[4][16*40];
  const int tid = threadIdx.x;
  const int wid = tid>>6, lane = tid&63;
  const int g = lane>>4, li = lane&15;

  const int V = wid*1024 + blockIdx.x;   // [0,4096)
  const int h = V>>8;
  const int rr = V&255;
  const int b = rr>>6, qw16 = rr&63;

  int w = 1024 >> h; if (w < 4) w = 4;
  const int qw0 = qw16*16;
  const int bh = b*NH + h;

  int mylo = qw0 - w + 1; if (mylo < 0) mylo = 0;
  const int kt_start = mylo >> 5;
  const int kt_end = (qw0 + 15) >> 5;

  const unsigned short* qbase = qk + ((size_t)(b*T_SEQ + qw0 + li)*2048 + h*64 + g*8);
  const bf16x8 aq0 = *reinterpret_cast<const bf16x8*>(qbase);
  const bf16x8 aq1 = *reinterpret_cast<const bf16x8*>(qbase + 32);

  f32x4 oacc[4] = {};
  float lsum[4] = {0.f,0.f,0.f,0.f};

  const unsigned short* kp = Kpack + (size_t)bh*32*4*512;
  const unsigned short* vp = Vpack + (size_t)bh*32*4*512;
  const int loff = lane*8;

  bf16x8 kf[4], kn[4], bv[4];
  #pragma unroll
  for (int f=0; f<4; f++)
    kf[f] = *reinterpret_cast<const bf16x8*>(kp + (kt_start*4 + f)*512 + loff);

  for (int kt = kt_start; kt <= kt_end; ++kt){
    #pragma unroll
    for (int d4=0; d4<4; d4++)
      bv[d4] = *reinterpret_cast<const bf16x8*>(vp + (kt*4 + d4)*512 + loff);
    {
      const int ktn = (kt < kt_end) ? kt+1 : kt_end;
      #pragma unroll
      for (int f=0; f<4; f++)
        kn[f] = *reinterpret_cast<const bf16x8*>(kp + (ktn*4 + f)*512 + loff);
    }

    f32x4 s0 = {}, s1 = {};
    s0 = MFMA16(aq0, kf[0], s0);
    s0 = MFMA16(aq1, kf[1], s0);
    s1 = MFMA16(aq0, kf[2], s1);
    s1 = MFMA16(aq1, kf[3], s1);

    const int k0 = kt*32;
    #pragma unroll
    for (int r=0;r<4;r++){
      const int t = qw0 + g*4 + r;
      const int ka = k0 + li;
      const int kb2 = ka + 16;
      const bool v0 = (ka <= t) && (ka > t - w);
      const bool v1 = (kb2 <= t) && (kb2 > t - w);
      const float p0 = v0 ? __expf(s0[r]*0.125f) : 0.f;
      const float p1 = v1 ? __expf(s1[r]*0.125f) : 0.f;
      lsum[r] += p0 + p1;
      const int q = g*4 + r;
      lP[wid][q*40 + li]      = f2bf(p0);
      lP[wid][q*40 + 16 + li] = f2bf(p1);
    }
    const bf16x8 pa = *reinterpret_cast<const bf16x8*>(&lP[wid][li*40 + g*8]);
    #pragma unroll
    for (int d4=0; d4<4; d4++)
      oacc[d4] = MFMA16(pa, bv[d4], oacc[d4]);
    #pragma unroll
    for (int i=0;i<4;i++) kf[i] = kn[i];
  }

  #pragma unroll
  for (int msk=1; msk<16; msk<<=1){
    #pragma unroll
    for (int r=0;r<4;r++) lsum[r] += __shfl_xor(lsum[r], msk, 64);
  }

  #pragma unroll
  for (int r=0;r<4;r++){
    const int t = qw0 + g*4 + r;
    const float gv = gates[(size_t)(b*T_SEQ + t)*NH + h];
    const float inv = gv / lsum[r];
    unsigned short* orow = gated + (size_t)(b*T_SEQ + t)*CEMB + h*64 + li;
    orow[0]  = f2bf(oacc[0][r]*inv);
    orow[16] = f2bf(oacc[1][r]*inv);
    orow[32] = f2bf(oacc[2][r]*inv);
    orow[48] = f2bf(oacc[3][r]*inv);
  }
}

extern "C" void kernel_launch(void* const* d_in, const int* in_sizes, int n_in,
                              void* d_out, int out_size, void* d_ws, size_t ws_size,
                              hipStream_t stream){
  const float* x     = (const float*)d_in[0];
  const float* Wqk   = (const float*)d_in[1];
  const float* bqk   = (const float*)d_in[2];
  const float* Wgate = (const float*)d_in[3];
  const float* bgate = (const float*)d_in[4];
  const float* Wproj = (const float*)d_in[5];
  const float* bproj = (const float*)d_in[6];
  float* out = (float*)d_out;

  // workspace layout (~56MB of the 256MB ws)
  unsigned short* x_bf   = (unsigned short*)d_ws;                 // 8MB
  unsigned short* WqkT   = x_bf   + (size_t)4096*1024;            // 4MB
  unsigned short* WprojT = WqkT   + (size_t)2048*1024;            // 2MB
  unsigned short* qkb    = WprojT + (size_t)1024*1024;            // 16MB (k-half unused)
  unsigned short* gated  = qkb    + (size_t)4096*2048;            // 8MB
  float*          gates  = (float*)(gated + (size_t)4096*1024);   // 256KB
  unsigned short* Kpack  = (unsigned short*)((char*)d_ws + (size_t)40*1024*1024);  // 8MB
  unsigned short* Vpack  = Kpack + (size_t)64*32*4*512;                            // 8MB

  prep_all_kernel<<<8192, 256, 0, stream>>>(x, x_bf, Wqk, WqkT, Wproj, WprojT, Wgate, bgate, gates);

  gemm_bt_kernel<true, 128, true, 8><<<512, 512, 0, stream>>>(x_bf, WqkT, bqk, qkb,
                                                              4096, 2048, 1024, Kpack, Vpack);
  attn_mfma_kernel<<<1024, 256, 0, stream>>>(qkb, Kpack, Vpack, gates, gated);
  gemm_bt_kernel<false, 64, false, 8><<<512, 512, 0, stream>>>(gated, WprojT, bproj, out,
                                                               4096, 1024, 1024, nullptr, nullptr);
}

// Round 20
// 89.473 us; speedup vs baseline: 1.0272x; 1.0272x over previous
//
#include <hip/hip_runtime.h>

typedef __attribute__((ext_vector_type(8))) short bf16x8;
typedef __attribute__((ext_vector_type(4))) float f32x4;

#define T_SEQ 1024
#define NH 16
#define CEMB 1024

__device__ __forceinline__ float asf(unsigned int u){ union{unsigned int i;float f;}x; x.i=u; return x.f; }
__device__ __forceinline__ float bf2f(unsigned short u){ return asf(((unsigned int)u)<<16); }
__device__ __forceinline__ unsigned short f2bf(float f){
  union{float f;unsigned int i;}x; x.f=f;
  unsigned int r = x.i + 0x7FFFu + ((x.i>>16)&1u);
  return (unsigned short)(r>>16);
}
__device__ __forceinline__ f32x4 MFMA16(bf16x8 a, bf16x8 b, f32x4 c){
  return __builtin_amdgcn_mfma_f32_16x16x32_bf16(a, b, c, 0,0,0);
}

// ---------------- fused prep, heavy-first: gates (0-1023) | wtrans (1024-4095) | cvt (4096-8191) ----------------
__global__ __launch_bounds__(256)
void prep_all_kernel(const float* __restrict__ x, unsigned short* __restrict__ x_bf,
                     const float* __restrict__ Wqk, unsigned short* __restrict__ WqkT,
                     const float* __restrict__ Wproj, unsigned short* __restrict__ WprojT,
                     const float* __restrict__ Wg, const float* __restrict__ bg,
                     float* __restrict__ gates){
  __shared__ float tile[32][33];
  const int tid = threadIdx.x;
  int blk = blockIdx.x;
  if (blk < 1024){
    // ---- gates (heaviest blocks first) ----
    const int lane = tid & 63;
    const int row  = blk*4 + (tid>>6);
    const float* xr = x + (size_t)row*CEMB;
    float acc[NH];
    #pragma unroll
    for (int h=0;h<NH;h++) acc[h]=0.f;
    for (int i=0;i<CEMB/64;i++){
      float xv = xr[i*64 + lane];
      const float4* wg = reinterpret_cast<const float4*>(Wg + (size_t)(i*64+lane)*NH);
      float4 a=wg[0], b=wg[1], c=wg[2], d=wg[3];
      acc[0]+=xv*a.x; acc[1]+=xv*a.y; acc[2]+=xv*a.z; acc[3]+=xv*a.w;
      acc[4]+=xv*b.x; acc[5]+=xv*b.y; acc[6]+=xv*b.z; acc[7]+=xv*b.w;
      acc[8]+=xv*c.x; acc[9]+=xv*c.y; acc[10]+=xv*c.z; acc[11]+=xv*c.w;
      acc[12]+=xv*d.x; acc[13]+=xv*d.y; acc[14]+=xv*d.z; acc[15]+=xv*d.w;
    }
    #pragma unroll
    for (int h=0;h<NH;h++){
      #pragma unroll
      for (int m=32;m;m>>=1) acc[h] += __shfl_xor(acc[h], m, 64);
    }
    float mx = -1e30f;
    #pragma unroll
    for (int h=0;h<NH;h++){ acc[h] += bg[h]; mx = fmaxf(mx, acc[h]); }
    float s = 0.f;
    #pragma unroll
    for (int h=0;h<NH;h++){ acc[h] = __expf(acc[h]-mx); s += acc[h]; }
    float g = 0.f;
    #pragma unroll
    for (int h=0;h<NH;h++) g = (lane==h) ? acc[h]/s : g;
    if (lane < NH) gates[(size_t)row*NH + lane] = g;
  } else if (blk < 4096){
    // ---- weight transposes ----
    blk -= 1024;
    const float* W; unsigned short* Wt; int R, C, bx, by;
    if (blk < 2048){ W = Wqk;   Wt = WqkT;   R = 1024; C = 2048; bx = blk & 63; by = blk >> 6; }
    else { blk -= 2048; W = Wproj; Wt = WprojT; R = 1024; C = 1024; bx = blk & 31; by = blk >> 5; }
    const int c0 = bx*32, r0 = by*32;
    const int tx = tid & 31, ty = tid >> 5;   // (32,8)
    #pragma unroll
    for (int i=0;i<32;i+=8) tile[ty+i][tx] = W[(size_t)(r0+ty+i)*C + c0 + tx];
    __syncthreads();
    #pragma unroll
    for (int i=0;i<32;i+=8) Wt[(size_t)(c0+ty+i)*R + r0 + tx] = f2bf(tile[tx][ty+i]);
  } else {
    // ---- cvt x -> bf16 ----
    int i = ((blk-4096)*256 + tid)*4;
    float4 v = *reinterpret_cast<const float4*>(x + i);
    ushort4 o; o.x=f2bf(v.x); o.y=f2bf(v.y); o.z=f2bf(v.z); o.w=f2bf(v.w);
    *reinterpret_cast<ushort4*>(x_bf + i) = o;
  }
}

// ---------------- bf16 MFMA GEMM, depth-2 counted-vmcnt pipeline ----------------
// NW=8 everywhere: gemm1 128x128 tile (wave 32x64, 2 blocks/CU = 16 waves/CU);
// gemm2 BM=64 (wave 16x64, 3 blocks/CU = 24 waves/CU).
// PACK: k-half blocks (bn>=8) emit Kpack/Vpack fragments from an LDS-staged tile.
template<bool OUT_BF16, int BM, bool PACK, int NW>
__global__ __launch_bounds__(NW*64)
void gemm_bt_kernel(const unsigned short* __restrict__ A, const unsigned short* __restrict__ Bt,
                    const float* __restrict__ bias, void* __restrict__ Cptr,
                    int M, int N, int K,
                    unsigned short* __restrict__ Kpack, unsigned short* __restrict__ Vpack){
  constexpr int WRN   = (NW==8) ? 4 : (BM==128 ? 2 : 1);
  constexpr int WCN   = NW/WRN;
  constexpr int WROWS = BM/WRN;
  constexpr int WCW   = 128/WCN;
  constexpr int MFRAG = WROWS/16;
  constexpr int NFRAG = WCW/16;
  constexpr int AISS  = BM/(NW*8);               // A stage issues per thread
  constexpr int BISS  = 128/(NW*8);              // B stage issues per thread
  constexpr int LDSN  = BM*64*2 + 128*64*2;
  __shared__ __align__(16) unsigned short smem[LDSN];
  unsigned short* lA0 = smem;
  unsigned short* lA1 = smem + BM*64;
  unsigned short* lB0 = smem + BM*64*2;
  unsigned short* lB1 = smem + BM*64*2 + 128*64;
  const int tid = threadIdx.x;
  const int wid = tid>>6, lane = tid&63;
  const int nbm = M/BM;
  const int bid = blockIdx.x;
  const int bm = bid % nbm, bn = bid / nbm;
  const int wr = (WRN==1) ? 0 : (wid/WCN);
  const int wc = (WCN==1) ? 0 : (wid%WCN);
  f32x4 acc[MFRAG][NFRAG] = {};

  const unsigned short* gA = A + (size_t)bm*BM*K;
  const unsigned short* gB = Bt + (size_t)bn*128*K;
  const int srow = lane>>3;
  const int schunk = lane&7;

#define GSTAGE(LA, LB, KK) do { \
  _Pragma("unroll") \
  for (int i_=0;i_<AISS;i_++){ \
    int rowi_ = (wid*AISS+i_)*8 + srow; \
    int cc_ = schunk ^ (rowi_ & 7); \
    __builtin_amdgcn_global_load_lds((const __attribute__((address_space(1))) void*)(gA + (size_t)rowi_*K + (KK) + cc_*8), \
        (__attribute__((address_space(3))) void*)&LA[(wid*AISS+i_)*512], 16, 0, 0); \
  } \
  _Pragma("unroll") \
  for (int i_=0;i_<BISS;i_++){ \
    int rowi_ = (wid*BISS+i_)*8 + srow; \
    int cc_ = schunk ^ (rowi_ & 7); \
    __builtin_amdgcn_global_load_lds((const __attribute__((address_space(1))) void*)(gB + (size_t)rowi_*K + (KK) + cc_*8), \
        (__attribute__((address_space(3))) void*)&LB[(wid*BISS+i_)*512], 16, 0, 0); \
  } \
} while(0)

#define GCOMPUTE(LA, LB) do { \
  _Pragma("unroll") \
  for (int ks_=0; ks_<2; ks_++){ \
    bf16x8 af_[MFRAG], bf_[NFRAG]; \
    _Pragma("unroll") \
    for (int m_=0;m_<MFRAG;m_++){ \
      int r_ = wr*WROWS + m_*16 + (lane&15); \
      int p_ = (ks_*4 + (lane>>4)) ^ (r_&7); \
      af_[m_] = *reinterpret_cast<const bf16x8*>(&LA[r_*64 + p_*8]); \
    } \
    _Pragma("unroll") \
    for (int n_=0;n_<NFRAG;n_++){ \
      int r_ = wc*WCW + n_*16 + (lane&15); \
      int p_ = (ks_*4 + (lane>>4)) ^ (r_&7); \
      bf_[n_] = *reinterpret_cast<const bf16x8*>(&LB[r_*64 + p_*8]); \
    } \
    _Pragma("unroll") \
    for (int m_=0;m_<MFRAG;m_++) \
      _Pragma("unroll") \
      for (int n_=0;n_<NFRAG;n_++) \
        acc[m_][n_] = __builtin_amdgcn_mfma_f32_16x16x32_bf16(af_[m_], bf_[n_], acc[m_][n_], 0,0,0); \
  } \
} while(0)

#define WAITL do { \
  if      constexpr (AISS+BISS==3) asm volatile("s_waitcnt vmcnt(3)" ::: "memory"); \
  else if constexpr (AISS+BISS==4) asm volatile("s_waitcnt vmcnt(4)" ::: "memory"); \
  else if constexpr (AISS+BISS==6) asm volatile("s_waitcnt vmcnt(6)" ::: "memory"); \
  else                             asm volatile("s_waitcnt vmcnt(8)" ::: "memory"); \
  __builtin_amdgcn_s_barrier(); \
  __builtin_amdgcn_sched_barrier(0); \
} while(0)

  GSTAGE(lA0, lB0, 0);
  GSTAGE(lA1, lB1, 64);
  for (int k0=0; k0<K-128; k0+=128){
    WAITL;
    GCOMPUTE(lA0, lB0);
    __builtin_amdgcn_s_barrier();
    __builtin_amdgcn_sched_barrier(0);
    GSTAGE(lA0, lB0, k0+128);
    WAITL;
    GCOMPUTE(lA1, lB1);
    __builtin_amdgcn_s_barrier();
    __builtin_amdgcn_sched_barrier(0);
    GSTAGE(lA1, lB1, k0+192);
  }
  WAITL;
  GCOMPUTE(lA0, lB0);
  asm volatile("s_waitcnt vmcnt(0)" ::: "memory");
  __builtin_amdgcn_s_barrier();
  __builtin_amdgcn_sched_barrier(0);
  GCOMPUTE(lA1, lB1);
#undef GSTAGE
#undef GCOMPUTE
#undef WAITL

  const int rq = lane>>4;
  const int cl = lane&15;

  if constexpr (PACK){
    if (bn >= 8){
      // ---- pack epilogue: stage tile (stride 136), emit Kpack/Vpack frags ----
      __syncthreads();
      #pragma unroll
      for (int n=0;n<NFRAG;n++){
        const int c_l = wc*WCW + n*16 + cl;
        const float bv = bias[bn*128 + c_l];
        #pragma unroll
        for (int m=0;m<MFRAG;m++){
          const int r_l = wr*WROWS + m*16 + rq*4;
          #pragma unroll
          for (int r=0;r<4;r++)
            smem[(r_l+r)*136 + c_l] = f2bf(acc[m][n][r] + bv);
        }
      }
      __syncthreads();
      const int b = bm>>3;
      const int ktg0 = (bm&7)*4;
      const int g = lane>>4, li = lane&15;
      const int kt_l = wid>>1;          // 0..3: 32-row kt tile
      const int hh   = wid&1;           // head half
      const int bh = b*NH + (bn-8)*2 + hh;
      const size_t fb = ((size_t)bh*32 + ktg0 + kt_l)*4;
      #pragma unroll
      for (int f=0; f<4; f++){
        // Kpack[bh][kt][f][lane][j] = K[kt*32+(f>>1)*16+li][(f&1)*32+g*8+j]
        uint4 kv = *reinterpret_cast<const uint4*>(
            &smem[(kt_l*32 + ((f>>1)<<4) + li)*136 + hh*64 + (f&1)*32 + g*8]);
        *reinterpret_cast<uint4*>(Kpack + ((fb + f)*64 + lane)*8) = kv;
        // Vpack[bh][kt][d4][lane][j] = K[kt*32+g*8+j][d4*16+li]   (d4 = f)
        unsigned short vv[8];
        #pragma unroll
        for (int j=0;j<8;j++) vv[j] = smem[(kt_l*32 + g*8 + j)*136 + hh*64 + f*16 + li];
        *reinterpret_cast<uint4*>(Vpack + ((fb + f)*64 + lane)*8) = *reinterpret_cast<const uint4*>(vv);
      }
      return;
    }
  }

  #pragma unroll
  for (int n=0;n<NFRAG;n++){
    int col = bn*128 + wc*WCW + n*16 + cl;
    float bv = bias[col];
    #pragma unroll
    for (int m=0;m<MFRAG;m++){
      int row = bm*BM + wr*WROWS + m*16 + rq*4;
      #pragma unroll
      for (int r=0;r<4;r++){
        float v = acc[m][n][r] + bv;
        if (OUT_BF16) ((unsigned short*)Cptr)[(size_t)(row+r)*N + col] = f2bf(v);
        else          ((float*)Cptr)[(size_t)(row+r)*N + col] = v;
      }
    }
  }
}

// ---------------- MFMA attention, no-max softmax, packed frags, NO split-K ----------------
__global__ __launch_bounds__(256)
void attn_mfma_kernel(const unsigned short* __restrict__ qk,
                      const unsigned short* __restrict__ Kpack,
                      const unsigned short* __restrict__ Vpack,
                      const float* __restrict__ gates, unsigned short* __restrict__ gated){
  __shared__ unsigned short lP[4][16*40];
  const int tid = threadIdx.x;
  const int wid = tid>>6, lane = tid&63;
  const int g = lane>>4, li = lane&15;

  const int V = wid*1024 + blockIdx.x;   // [0,4096)
  const int h = V>>8;
  const int rr = V&255;
  const int b = rr>>6, qw16 = rr&63;

  int w = 1024 >> h; if (w < 4) w = 4;
  const int qw0 = qw16*16;
  const int bh = b*NH + h;

  int mylo = qw0 - w + 1; if (mylo < 0) mylo = 0;
  const int kt_start = mylo >> 5;
  const int kt_end = (qw0 + 15) >> 5;

  const unsigned short* qbase = qk + ((size_t)(b*T_SEQ + qw0 + li)*2048 + h*64 + g*8);
  const bf16x8 aq0 = *reinterpret_cast<const bf16x8*>(qbase);
  const bf16x8 aq1 = *reinterpret_cast<const bf16x8*>(qbase + 32);

  f32x4 oacc[4] = {};
  float lsum[4] = {0.f,0.f,0.f,0.f};

  const unsigned short* kp = Kpack + (size_t)bh*32*4*512;
  const unsigned short* vp = Vpack + (size_t)bh*32*4*512;
  const int loff = lane*8;

  bf16x8 kf[4], kn[4], bv[4];
  #pragma unroll
  for (int f=0; f<4; f++)
    kf[f] = *reinterpret_cast<const bf16x8*>(kp + (kt_start*4 + f)*512 + loff);

  for (int kt = kt_start; kt <= kt_end; ++kt){
    #pragma unroll
    for (int d4=0; d4<4; d4++)
      bv[d4] = *reinterpret_cast<const bf16x8*>(vp + (kt*4 + d4)*512 + loff);
    {
      const int ktn = (kt < kt_end) ? kt+1 : kt_end;
      #pragma unroll
      for (int f=0; f<4; f++)
        kn[f] = *reinterpret_cast<const bf16x8*>(kp + (ktn*4 + f)*512 + loff);
    }

    f32x4 s0 = {}, s1 = {};
    s0 = MFMA16(aq0, kf[0], s0);
    s0 = MFMA16(aq1, kf[1], s0);
    s1 = MFMA16(aq0, kf[2], s1);
    s1 = MFMA16(aq1, kf[3], s1);

    const int k0 = kt*32;
    #pragma unroll
    for (int r=0;r<4;r++){
      const int t = qw0 + g*4 + r;
      const int ka = k0 + li;
      const int kb2 = ka + 16;
      const bool v0 = (ka <= t) && (ka > t - w);
      const bool v1 = (kb2 <= t) && (kb2 > t - w);
      const float p0 = v0 ? __expf(s0[r]*0.125f) : 0.f;
      const float p1 = v1 ? __expf(s1[r]*0.125f) : 0.f;
      lsum[r] += p0 + p1;
      const int q = g*4 + r;
      lP[wid][q*40 + li]      = f2bf(p0);
      lP[wid][q*40 + 16 + li] = f2bf(p1);
    }
    const bf16x8 pa = *reinterpret_cast<const bf16x8*>(&lP[wid][li*40 + g*8]);
    #pragma unroll
    for (int d4=0; d4<4; d4++)
      oacc[d4] = MFMA16(pa, bv[d4], oacc[d4]);
    #pragma unroll
    for (int i=0;i<4;i++) kf[i] = kn[i];
  }

  #pragma unroll
  for (int msk=1; msk<16; msk<<=1){
    #pragma unroll
    for (int r=0;r<4;r++) lsum[r] += __shfl_xor(lsum[r], msk, 64);
  }

  #pragma unroll
  for (int r=0;r<4;r++){
    const int t = qw0 + g*4 + r;
    const float gv = gates[(size_t)(b*T_SEQ + t)*NH + h];
    const float inv = gv / lsum[r];
    unsigned short* orow = gated + (size_t)(b*T_SEQ + t)*CEMB + h*64 + li;
    orow[0]  = f2bf(oacc[0][r]*inv);
    orow[16] = f2bf(oacc[1][r]*inv);
    orow[32] = f2bf(oacc[2][r]*inv);
    orow[48] = f2bf(oacc[3][r]*inv);
  }
}

extern "C" void kernel_launch(void* const* d_in, const int* in_sizes, int n_in,
                              void* d_out, int out_size, void* d_ws, size_t ws_size,
                              hipStream_t stream){
  const float* x     = (const float*)d_in[0];
  const float* Wqk   = (const float*)d_in[1];
  const float* bqk   = (const float*)d_in[2];
  const float* Wgate = (const float*)d_in[3];
  const float* bgate = (const float*)d_in[4];
  const float* Wproj = (const float*)d_in[5];
  const float* bproj = (const float*)d_in[6];
  float* out = (float*)d_out;

  // workspace layout (~56MB of the 256MB ws)
  unsigned short* x_bf   = (unsigned short*)d_ws;                 // 8MB
  unsigned short* WqkT   = x_bf   + (size_t)4096*1024;            // 4MB
  unsigned short* WprojT = WqkT   + (size_t)2048*1024;            // 2MB
  unsigned short* qkb    = WprojT + (size_t)1024*1024;            // 16MB (k-half unused)
  unsigned short* gated  = qkb    + (size_t)4096*2048;            // 8MB
  float*          gates  = (float*)(gated + (size_t)4096*1024);   // 256KB
  unsigned short* Kpack  = (unsigned short*)((char*)d_ws + (size_t)40*1024*1024);  // 8MB
  unsigned short* Vpack  = Kpack + (size_t)64*32*4*512;                            // 8MB

  prep_all_kernel<<<8192, 256, 0, stream>>>(x, x_bf, Wqk, WqkT, Wproj, WprojT, Wgate, bgate, gates);

  gemm_bt_kernel<true, 128, true, 8><<<512, 512, 0, stream>>>(x_bf, WqkT, bqk, qkb,
                                                              4096, 2048, 1024, Kpack, Vpack);
  attn_mfma_kernel<<<1024, 256, 0, stream>>>(qkb, Kpack, Vpack, gates, gated);
  gemm_bt_kernel<false, 64, false, 8><<<512, 512, 0, stream>>>(gated, WprojT, bproj, out,
                                                               4096, 1024, 1024, nullptr, nullptr);
}